// Round 5
// baseline (700.108 us; speedup 1.0000x reference)
//
#include <hip/hip_runtime.h>
#include <utility>
#include <cstddef>

#define NCOLS 985        // 1 + 16 + 136 + 816 + 16
#define CW    32         // chunk width (columns)
#define NCH   31         // 30*32 + 25 = 985
#define ROWS  64         // rows per wave (lane = row)
#define SLABDW (ROWS * CW)   // 2048 dwords = 8 KB per wave

// ---- compile-time combinatorial decoders (match itertools order; validated r2/r3) ----
constexpr int pair_i_f(int p){ int i=0; while (p >= 16-i){ p -= 16-i; ++i; } return i; }
constexpr int pair_j_f(int p){ int i=0; while (p >= 16-i){ p -= 16-i; ++i; } return i+p; }
constexpr int tcount(int i){ return (16-i)*(17-i)/2; }
constexpr int trip_i_f(int t){ int i=0; while (t >= tcount(i)){ t -= tcount(i); ++i; } return i; }
constexpr int trip_j_f(int t){ int i=0; while (t >= tcount(i)){ t -= tcount(i); ++i; }
                               int j=i; while (t >= 16-j){ t -= 16-j; ++j; } return j; }
constexpr int trip_k_f(int t){ int i=0; while (t >= tcount(i)){ t -= tcount(i); ++i; }
                               int j=i; while (t >= 16-j){ t -= 16-j; ++j; } return j+t; }

// ---- one output column, fully static register indices ----
template<int E>
__device__ __forceinline__ float term(const float (&zc)[16]) {
  if constexpr (E >= NCOLS) {
    return 0.0f;                        // pad columns (never stored)
  } else if constexpr (E == 0) {
    return 1.0f;
  } else if constexpr (E <= 16) {
    return zc[E-1];
  } else if constexpr (E < 153) {
    constexpr int p = E - 17;
    return zc[pair_i_f(p)] * zc[pair_j_f(p)];
  } else if constexpr (E < 969) {
    constexpr int t = E - 153;
    return (zc[trip_i_f(t)] * zc[trip_j_f(t)]) * zc[trip_k_f(t)];
  } else {
    return __sinf(zc[E - 969]);
  }
}

template<int C0, int Q>
__device__ __forceinline__ float4 quad(const float (&zc)[16]) {
  constexpr int B = C0 + Q*4;
  return make_float4(term<B+0>(zc), term<B+1>(zc), term<B+2>(zc), term<B+3>(zc));
}

// lane = row: write this row's 32 cols as 8 x ds_write_b128, XOR-swizzled quads.
// Per 8-lane group (rows r..r+7), quads q^(r&7) cover slots 0..7 once each ->
// all 32 banks hit exactly once per 128B cycle: conflict-free.
template<int C>
__device__ __forceinline__ void compute_chunk(const float (&zc)[16], float* slw, int l) {
  constexpr int C0 = C * CW;
  float4* sq = (float4*)slw;
  const int rb = l * 8;       // 8 quads per row
  const int s  = l & 7;
  sq[rb + (0^s)] = quad<C0,0>(zc);
  sq[rb + (1^s)] = quad<C0,1>(zc);
  sq[rb + (2^s)] = quad<C0,2>(zc);
  sq[rb + (3^s)] = quad<C0,3>(zc);
  sq[rb + (4^s)] = quad<C0,4>(zc);
  sq[rb + (5^s)] = quad<C0,5>(zc);
  sq[rb + (6^s)] = quad<C0,6>(zc);
  sq[rb + (7^s)] = quad<C0,7>(zc);
}

// drain: lane = (c = l&31, dr = l>>5); each iter covers 2 rows x 32 contiguous
// cols (2-way bank alias = free). Stores: 2 x 128B contiguous segments.
template<int C, bool RT>
__device__ __forceinline__ void drain(const float* slw, float* __restrict__ out,
                                      unsigned idx0, int l, int nrows) {
  constexpr int C0  = C * CW;
  constexpr int LEN = (C0 + CW <= NCOLS) ? CW : (NCOLS - C0);
  const int dr = l >> 5, c = l & 31;
  #pragma unroll 8
  for (int rp = 0; rp < 32; ++rp) {
    const int row = rp*2 + dr;
    const int di  = (row << 5) + ((((c >> 2) ^ (row & 7)) << 2) | (c & 3));
    const float v = slw[di];
    bool ok = true;
    if constexpr (LEN < CW) ok = (c < LEN);
    if constexpr (RT)       ok = ok && (row < nrows);
    if (ok) out[idx0 + (unsigned)row * (unsigned)NCOLS + (unsigned)C0] = v;
  }
}

template<int C, bool RT>
__device__ __forceinline__ void chunk_all(const float (&zc)[16], float* slw,
                                          float* __restrict__ out,
                                          int l, unsigned idx0, int nrows) {
  compute_chunk<C>(zc, slw, l);
  __builtin_amdgcn_sched_barrier(0);   // write -> read order (same-wave DS)
  drain<C, RT>(slw, out, idx0, l, nrows);
  __builtin_amdgcn_sched_barrier(0);   // read -> next chunk's writes
}

template<bool RT, int... Cs>
__device__ __forceinline__ void run_chunks(const float (&zc)[16], float* slw,
                                           float* __restrict__ out,
                                           int l, unsigned idx0, int nrows,
                                           std::integer_sequence<int, Cs...>) {
  (chunk_all<Cs, RT>(zc, slw, out, l, idx0, nrows), ...);
}

__global__ __launch_bounds__(256) void sindy_kernel(const float* __restrict__ z,
                                                    const float* __restrict__ dz,
                                                    float* __restrict__ out, int batch) {
  __shared__ alignas(16) float slab[4][SLABDW];   // 8 KB per wave, 32 KB per block

  const int w = threadIdx.x >> 6;
  const int l = threadIdx.x & 63;
  const int wrow0 = (blockIdx.x * 4 + w) * ROWS;
  if (wrow0 >= batch) return;                     // no block barriers -> safe

  // lane l owns row wrow0 + l: load its 16 zc values into VGPRs
  const int lrow = (wrow0 + l < batch) ? (wrow0 + l) : (batch - 1);
  float zc[16];
  {
    const float4* zp = (const float4*)(z  + (size_t)lrow * 8);
    const float4* dp = (const float4*)(dz + (size_t)lrow * 8);
    float4 a = zp[0], b = zp[1], cc = dp[0], d = dp[1];
    zc[0]=a.x;  zc[1]=a.y;  zc[2]=a.z;  zc[3]=a.w;
    zc[4]=b.x;  zc[5]=b.y;  zc[6]=b.z;  zc[7]=b.w;
    zc[8]=cc.x; zc[9]=cc.y; zc[10]=cc.z;zc[11]=cc.w;
    zc[12]=d.x; zc[13]=d.y; zc[14]=d.z; zc[15]=d.w;
  }

  float* slw = slab[w];
  const int c = l & 31;
  const unsigned idx0 = (unsigned)wrow0 * (unsigned)NCOLS + (unsigned)c;
  const int nrows = batch - wrow0;

  if (nrows >= ROWS) {
    run_chunks<false>(zc, slw, out, l, idx0, ROWS,
                      std::make_integer_sequence<int, NCH>{});
  } else {
    run_chunks<true>(zc, slw, out, l, idx0, nrows,
                     std::make_integer_sequence<int, NCH>{});
  }
}

extern "C" void kernel_launch(void* const* d_in, const int* in_sizes, int n_in,
                              void* d_out, int out_size, void* d_ws, size_t ws_size,
                              hipStream_t stream) {
  const float* z  = (const float*)d_in[0];
  const float* dz = (const float*)d_in[1];
  float* out = (float*)d_out;
  const int batch = in_sizes[0] / 8;   // LATENT_DIM = 8

  const int blocks = (batch + 4*ROWS - 1) / (4*ROWS);   // 256 rows per block
  sindy_kernel<<<blocks, 256, 0, stream>>>(z, dz, out, batch);
}

// Round 6
// 128.910 us; speedup vs baseline: 5.4310x; 5.4310x over previous
//
#include <hip/hip_runtime.h>
#include <cstddef>

#define NCOLS 985
#define RPW   16          // rows per wave
#define GSTR  176         // per-wave G slots: [0]=1, [1..16]=zc, [17..152]=pairs, [153..168]=sin, [169..175]=0

__global__ __launch_bounds__(256) void sindy_kernel(const float* __restrict__ z,
                                                    const float* __restrict__ dz,
                                                    float* __restrict__ out, int batch) {
  __shared__ unsigned short mtab[1024];   // col -> a | b<<8 (G indices)
  __shared__ unsigned short ptab[136];    // pair p -> i | j<<4
  __shared__ float G[4][GSTR];            // one factor array per wave

  const int tid = threadIdx.x;

  // ---- build static tables (once per block, integer math) ----
  for (int e = tid; e < 1024; e += 256) {
    int a, b;
    if (e < 153)       { a = (e == 0) ? 0 : e; b = 0; }          // 1, zc, pairs: G[col]*1
    else if (e < 969)  {                                          // triples
      int t = e - 153, i = 0;
      for (;;) { int c = (16 - i) * (17 - i) / 2; if (t < c) break; t -= c; ++i; }
      int j = i; while (t >= 16 - j) { t -= 16 - j; ++j; }
      int k = j + t;
      int p = i * 16 - i * (i - 1) / 2 + (j - i);                 // pidx(i,j)
      a = 17 + p; b = 1 + k;                                      // (zi*zj) * zk
    }
    else if (e < 985)  { a = 153 + (e - 969); b = 0; }            // sines
    else               { a = 169; b = 169; }                      // pad -> 0*0
    mtab[e] = (unsigned short)(a | (b << 8));
  }
  for (int e = tid; e < 136; e += 256) {
    int p = e, i = 0; while (p >= 16 - i) { p -= 16 - i; ++i; }
    ptab[e] = (unsigned short)(i | ((i + p) << 4));
  }
  __syncthreads();   // tables ready (only block-wide barrier)

  const int w = tid >> 6, l = tid & 63;

  // ---- hoist per-lane static table entries into VGPRs (fixed across rows) ----
  unsigned short mt[16];
  #pragma unroll
  for (int wd = 0; wd < 16; ++wd) mt[wd] = mtab[wd * 64 + l];
  const unsigned pe0 = ptab[l];                                   // pair l
  const unsigned pe1 = ptab[64 + l];                              // pair 64+l (<128)
  const unsigned pe2 = ptab[(128 + l < 136) ? (128 + l) : 135];   // pair 128+l (l<8)

  float* Gw = G[w];
  const int row0 = (blockIdx.x * 4 + w) * RPW;
  if (row0 >= batch) return;

  for (int rr = 0; rr < RPW; ++rr) {
    const int row = row0 + rr;
    if (row >= batch) break;                                      // wave-uniform

    // ---- stage G[0..16] (1, zc) and zero pad 169..175 ----
    float gval = 0.f;
    if (l == 0)       gval = 1.0f;
    else if (l < 9)   gval = z [(size_t)row * 8 + (l - 1)];
    else if (l < 17)  gval = dz[(size_t)row * 8 + (l - 9)];
    const int gaddr = (l < 17) ? l : (152 + l);                   // 17..23 -> 169..175
    if (l < 24) Gw[gaddr] = gval;

    // sines: lane l<16 needs zc[l] = lane (l+1)'s gval
    const float sv = __shfl(gval, l + 1);
    if (l < 16) Gw[153 + l] = __sinf(sv);
    __builtin_amdgcn_sched_barrier(0);    // pin: G base writes before pair gathers

    // ---- stage pairs G[17..152] (reads follow writes: same-wave DS is in-order) ----
    {
      float a0 = Gw[1 + (pe0 & 15)], b0 = Gw[1 + (pe0 >> 4)];
      Gw[17 + l] = a0 * b0;                                       // pairs 0..63
      float a1 = Gw[1 + (pe1 & 15)], b1 = Gw[1 + (pe1 >> 4)];
      Gw[17 + 64 + l] = a1 * b1;                                  // pairs 64..127
      if (l < 8) {
        float a2 = Gw[1 + (pe2 & 15)], b2 = Gw[1 + (pe2 >> 4)];
        Gw[17 + 128 + l] = a2 * b2;                               // pairs 128..135
      }
    }
    __builtin_amdgcn_sched_barrier(0);    // pin: pair writes before main gathers

    // ---- main loop: 16 windows x 64 cols, 2 gathers + 1 mul + 1 store each ----
    float* orow = out + (size_t)row * NCOLS;
    #pragma unroll
    for (int wd = 0; wd < 16; ++wd) {
      const unsigned e = mt[wd];
      const float v = Gw[e & 255] * Gw[e >> 8];
      if (wd < 15)                 orow[wd * 64 + l] = v;         // 256B contiguous
      else if (l < NCOLS - 960)    orow[960 + l] = v;             // tail: 25 cols
    }
    __builtin_amdgcn_sched_barrier(0);    // pin: this row's gathers before next row's staging writes
  }
}

extern "C" void kernel_launch(void* const* d_in, const int* in_sizes, int n_in,
                              void* d_out, int out_size, void* d_ws, size_t ws_size,
                              hipStream_t stream) {
  const float* z  = (const float*)d_in[0];
  const float* dz = (const float*)d_in[1];
  float* out = (float*)d_out;
  const int batch = in_sizes[0] / 8;   // LATENT_DIM = 8

  // 64 rows per block (4 waves x 16 rows) -> 2048 blocks, 8 blocks/CU, 32 waves/CU
  const int blocks = (batch + 4 * RPW - 1) / (4 * RPW);
  sindy_kernel<<<blocks, 256, 0, stream>>>(z, dz, out, batch);
}

// Round 7
// 128.796 us; speedup vs baseline: 5.4358x; 1.0009x over previous
//
#include <hip/hip_runtime.h>
#include <cstddef>

#define NCOLS 985
#define RPW   16          // rows per wave
#define GSTR  176         // per-wave G slots: [0]=1, [1..16]=zc, [17..152]=pairs, [153..168]=sin, [169..175]=0

__global__ __launch_bounds__(256) void sindy_kernel(const float* __restrict__ z,
                                                    const float* __restrict__ dz,
                                                    float* __restrict__ out, int batch,
                                                    int nwaves) {
  __shared__ unsigned short mtab[1024];   // col -> a | b<<8 (G indices)
  __shared__ unsigned short ptab[136];    // pair p -> i | j<<4
  __shared__ float G[4][GSTR];            // one factor array per wave

  const int tid = threadIdx.x;

  // ---- build static tables (once per block, integer math) ----
  for (int e = tid; e < 1024; e += 256) {
    int a, b;
    if (e < 153)       { a = (e == 0) ? 0 : e; b = 0; }          // 1, zc, pairs: G[col]*1
    else if (e < 969)  {                                          // triples
      int t = e - 153, i = 0;
      for (;;) { int c = (16 - i) * (17 - i) / 2; if (t < c) break; t -= c; ++i; }
      int j = i; while (t >= 16 - j) { t -= 16 - j; ++j; }
      int k = j + t;
      int p = i * 16 - i * (i - 1) / 2 + (j - i);                 // pidx(i,j)
      a = 17 + p; b = 1 + k;                                      // (zi*zj) * zk
    }
    else if (e < 985)  { a = 153 + (e - 969); b = 0; }            // sines
    else               { a = 169; b = 169; }                      // pad -> 0*0
    mtab[e] = (unsigned short)(a | (b << 8));
  }
  for (int e = tid; e < 136; e += 256) {
    int p = e, i = 0; while (p >= 16 - i) { p -= 16 - i; ++i; }
    ptab[e] = (unsigned short)(i | ((i + p) << 4));
  }
  __syncthreads();   // tables ready (only block-wide barrier)

  const int w = tid >> 6, l = tid & 63;

  // ---- hoist per-lane static table entries into VGPRs (fixed across rows) ----
  unsigned short mt[16];
  #pragma unroll
  for (int wd = 0; wd < 16; ++wd) mt[wd] = mtab[wd * 64 + l];
  const unsigned pe0 = ptab[l];                                   // pair l
  const unsigned pe1 = ptab[64 + l];                              // pair 64+l (<128)
  const unsigned pe2 = ptab[(128 + l < 136) ? (128 + l) : 135];   // pair 128+l (l<8)

  float* Gw = G[w];
  const int gid = blockIdx.x * 4 + w;   // global wave id: rows gid, gid+nwaves, ...

  for (int rr = 0; rr < RPW; ++rr) {
    const int row = gid + rr * nwaves;  // dense sweeping band across all waves
    if (row >= batch) break;            // wave-uniform

    // ---- stage G[0..16] (1, zc) and zero pad 169..175 ----
    float gval = 0.f;
    if (l == 0)       gval = 1.0f;
    else if (l < 9)   gval = z [(size_t)row * 8 + (l - 1)];
    else if (l < 17)  gval = dz[(size_t)row * 8 + (l - 9)];
    const int gaddr = (l < 17) ? l : (152 + l);                   // 17..23 -> 169..175
    if (l < 24) Gw[gaddr] = gval;

    // sines: lane l<16 needs zc[l] = lane (l+1)'s gval
    const float sv = __shfl(gval, l + 1);
    if (l < 16) Gw[153 + l] = __sinf(sv);
    __builtin_amdgcn_sched_barrier(0);    // pin: G base writes before pair gathers

    // ---- stage pairs G[17..152] (reads follow writes: same-wave DS is in-order) ----
    {
      float a0 = Gw[1 + (pe0 & 15)], b0 = Gw[1 + (pe0 >> 4)];
      Gw[17 + l] = a0 * b0;                                       // pairs 0..63
      float a1 = Gw[1 + (pe1 & 15)], b1 = Gw[1 + (pe1 >> 4)];
      Gw[17 + 64 + l] = a1 * b1;                                  // pairs 64..127
      if (l < 8) {
        float a2 = Gw[1 + (pe2 & 15)], b2 = Gw[1 + (pe2 >> 4)];
        Gw[17 + 128 + l] = a2 * b2;                               // pairs 128..135
      }
    }
    __builtin_amdgcn_sched_barrier(0);    // pin: pair writes before main gathers

    // ---- main loop: 16 windows x 64 cols, 2 gathers + 1 mul + 1 store each ----
    float* orow = out + (size_t)row * NCOLS;
    #pragma unroll
    for (int wd = 0; wd < 16; ++wd) {
      const unsigned e = mt[wd];
      const float v = Gw[e & 255] * Gw[e >> 8];
      if (wd < 15)                 orow[wd * 64 + l] = v;         // 256B contiguous
      else if (l < NCOLS - 960)    orow[960 + l] = v;             // tail: 25 cols
    }
    __builtin_amdgcn_sched_barrier(0);    // pin: this row's gathers before next row's staging writes
  }
}

extern "C" void kernel_launch(void* const* d_in, const int* in_sizes, int n_in,
                              void* d_out, int out_size, void* d_ws, size_t ws_size,
                              hipStream_t stream) {
  const float* z  = (const float*)d_in[0];
  const float* dz = (const float*)d_in[1];
  float* out = (float*)d_out;
  const int batch = in_sizes[0] / 8;   // LATENT_DIM = 8

  // 8192 waves (2048 blocks); wave g writes rows g, g+8192, ... -> dense sweep
  const int nwaves = (batch + RPW - 1) / RPW;
  const int blocks = (nwaves + 3) / 4;
  sindy_kernel<<<blocks, 256, 0, stream>>>(z, dz, out, batch, nwaves);
}

// Round 8
// 113.363 us; speedup vs baseline: 6.1758x; 1.1361x over previous
//
#include <hip/hip_runtime.h>
#include <cstddef>

#define NCOLS 985
#define TROWS 8                    // rows per LDS tile
#define TILEF (TROWS * NCOLS)      // 7880 floats per tile
#define NT4   (TILEF / 4)          // 1970 float4 units per tile (7880 % 4 == 0)
#define GSTR  176                  // per-wave G slots

__global__ __launch_bounds__(256) void sindy_kernel(const float* __restrict__ z,
                                                    const float* __restrict__ dz,
                                                    float* __restrict__ out, int batch,
                                                    int ntiles) {
  __shared__ unsigned short mtab[1024];   // col -> a | b<<8 (G indices)
  __shared__ unsigned short ptab[136];    // pair p -> i | j<<4
  __shared__ float G[4][GSTR];            // per-wave factor array
  __shared__ alignas(16) float rowbuf[TILEF];   // 31520 B staging tile

  const int tid = threadIdx.x;

  // ---- build static tables (once per block) ----
  for (int e = tid; e < 1024; e += 256) {
    int a, b;
    if (e < 153)       { a = (e == 0) ? 0 : e; b = 0; }
    else if (e < 969)  {
      int t = e - 153, i = 0;
      for (;;) { int c = (16 - i) * (17 - i) / 2; if (t < c) break; t -= c; ++i; }
      int j = i; while (t >= 16 - j) { t -= 16 - j; ++j; }
      int k = j + t;
      int p = i * 16 - i * (i - 1) / 2 + (j - i);
      a = 17 + p; b = 1 + k;
    }
    else if (e < 985)  { a = 153 + (e - 969); b = 0; }
    else               { a = 169; b = 169; }
    mtab[e] = (unsigned short)(a | (b << 8));
  }
  for (int e = tid; e < 136; e += 256) {
    int p = e, i = 0; while (p >= 16 - i) { p -= 16 - i; ++i; }
    ptab[e] = (unsigned short)(i | ((i + p) << 4));
  }
  __syncthreads();

  const int w = tid >> 6, l = tid & 63;

  // per-lane static table entries in VGPRs (fixed across rows)
  unsigned short mt[16];
  #pragma unroll
  for (int wd = 0; wd < 16; ++wd) mt[wd] = mtab[wd * 64 + l];
  const unsigned pe0 = ptab[l];
  const unsigned pe1 = ptab[64 + l];
  const unsigned pe2 = ptab[(128 + l < 136) ? (128 + l) : 135];

  float* Gw = G[w];

  for (int tile = blockIdx.x; tile < ntiles; tile += gridDim.x) {
    const int trow0 = tile * TROWS;
    const int nrows = (batch - trow0 < TROWS) ? (batch - trow0) : TROWS;

    // ---- compute phase: wave w fills tile-local rows {2w, 2w+1} into rowbuf ----
    #pragma unroll
    for (int rr = 0; rr < 2; ++rr) {
      const int lr  = w * 2 + rr;           // tile-local row
      const int row = trow0 + lr;           // global row (wave-uniform)
      if (row < batch) {
        // stage G[0..16] (1, zc) + zero pad 169..175
        float gval = 0.f;
        if (l == 0)       gval = 1.0f;
        else if (l < 9)   gval = z [(size_t)row * 8 + (l - 1)];
        else if (l < 17)  gval = dz[(size_t)row * 8 + (l - 9)];
        const int gaddr = (l < 17) ? l : (152 + l);
        if (l < 24) Gw[gaddr] = gval;

        const float sv = __shfl(gval, l + 1);
        if (l < 16) Gw[153 + l] = __sinf(sv);
        __builtin_amdgcn_sched_barrier(0);    // G base writes before pair gathers

        // pairs G[17..152] (same-wave DS is in-order)
        {
          float a0 = Gw[1 + (pe0 & 15)], b0 = Gw[1 + (pe0 >> 4)];
          Gw[17 + l] = a0 * b0;
          float a1 = Gw[1 + (pe1 & 15)], b1 = Gw[1 + (pe1 >> 4)];
          Gw[17 + 64 + l] = a1 * b1;
          if (l < 8) {
            float a2 = Gw[1 + (pe2 & 15)], b2 = Gw[1 + (pe2 >> 4)];
            Gw[17 + 128 + l] = a2 * b2;
          }
        }
        __builtin_amdgcn_sched_barrier(0);    // pair writes before main gathers

        // main: 16 windows x 64 cols -> rowbuf (2 gathers + mul + ds_write)
        float* rb = rowbuf + lr * NCOLS;
        #pragma unroll
        for (int wd = 0; wd < 16; ++wd) {
          const unsigned e = mt[wd];
          const float v = Gw[e & 255] * Gw[e >> 8];
          if (wd < 15)              rb[wd * 64 + l] = v;
          else if (l < NCOLS - 960) rb[960 + l] = v;
        }
        __builtin_amdgcn_sched_barrier(0);    // row gathers before next row's G writes
      }
    }
    __syncthreads();   // tile fully staged

    // ---- drain phase: flat, 16B-aligned, single-pass float4 stores ----
    if (nrows == TROWS) {
      float4* __restrict__ dst = (float4*)(out + (size_t)tile * TILEF);
      const float4* srcq = (const float4*)rowbuf;
      #pragma unroll 4
      for (int u = tid; u < NT4; u += 256) {
        dst[u] = srcq[u];
      }
    } else {
      // partial last tile: dword drain
      const int nel = nrows * NCOLS;
      float* __restrict__ dst = out + (size_t)tile * TILEF;
      for (int u = tid; u < nel; u += 256) dst[u] = rowbuf[u];
    }
    __syncthreads();   // drain done before next tile's compute overwrites rowbuf
  }
}

extern "C" void kernel_launch(void* const* d_in, const int* in_sizes, int n_in,
                              void* d_out, int out_size, void* d_ws, size_t ws_size,
                              hipStream_t stream) {
  const float* z  = (const float*)d_in[0];
  const float* dz = (const float*)d_in[1];
  float* out = (float*)d_out;
  const int batch = in_sizes[0] / 8;   // LATENT_DIM = 8

  const int ntiles = (batch + TROWS - 1) / TROWS;   // 16384
  const int blocks = 2048;                           // 8 tiles per block
  sindy_kernel<<<blocks, 256, 0, stream>>>(z, dz, out, batch, ntiles);
}